// Round 3
// baseline (227.143 us; speedup 1.0000x reference)
//
#include <hip/hip_runtime.h>
#include <math.h>

#define TT 8
#define NN 10000
#define EE 32768
#define CC 40
#define EPSV 1e-05f

constexpr float INV3 = 0.57735026918962576f;
constexpr float INV6 = 0.40824829046386302f;
constexpr float N0F  = 0.22360679774997896f;
constexpr float N1OF = 0.22360679774997896f;
constexpr float N1EF = 0.5f;

constexpr float CTab[8] = {1.f, 0.70710678118654752f, 0.f, -0.70710678118654752f,
                           -1.f, -0.70710678118654752f, 0.f, 0.70710678118654752f};
constexpr float STab[8] = {0.f, 0.70710678118654752f, 1.f, 0.70710678118654752f,
                           0.f, -0.70710678118654752f, -1.f, -0.70710678118654752f};

typedef __attribute__((ext_vector_type(8))) short short8;
typedef __attribute__((ext_vector_type(4))) float f32x4;

__device__ __forceinline__ void atomAdd(float* p, float v) {
  __hip_atomic_fetch_add(p, v, __ATOMIC_RELAXED, __HIP_MEMORY_SCOPE_AGENT);
}

// fp32 -> bf16 bits (RNE)
__device__ __forceinline__ short f2bfs(float f) {
  unsigned u = __builtin_bit_cast(unsigned, f);
  u = (u + 0x7fffu + ((u >> 16) & 1u)) >> 16;
  return (short)u;
}

// ---------------- pack W1 (48x48) and W2 (48x416) into MFMA B-fragment order, bf16 ----
__global__ __launch_bounds__(256) void k_prep(const float* __restrict__ W1,
                                              const float* __restrict__ W2,
                                              short* __restrict__ W1F,
                                              short* __restrict__ W2F) {
  int idx = blockIdx.x * 256 + threadIdx.x;
  const int tot1 = 3 * 2 * 64 * 8;
  const int tot2 = 26 * 2 * 64 * 8;
  if (idx < tot1) {
    int elem = idx & 7, lane = (idx >> 3) & 63, kt = (idx >> 9) & 1, nt = idx >> 10;
    int j = kt * 32 + ((lane >> 4) << 2) + (elem & 3) + ((elem >> 2) << 4);
    int n = nt * 16 + (lane & 15);
    W1F[idx] = (j < 48) ? f2bfs(W1[j * 48 + n]) : (short)0;
  } else if (idx < tot1 + tot2) {
    int id2 = idx - tot1;
    int elem = id2 & 7, lane = (id2 >> 3) & 63, kt = (id2 >> 9) & 1, ck = id2 >> 10;
    int j = kt * 32 + ((lane >> 4) << 2) + (elem & 3) + ((elem >> 2) << 4);
    int n = ck * 16 + (lane & 15);
    W2F[id2] = (j < 48) ? f2bfs(W2[j * 416 + n]) : (short)0;
  }
}

// ---------------- spectral conv ----------------
__global__ __launch_bounds__(256) void k_spec(const float* __restrict__ x,
                                              const float* __restrict__ wr,
                                              const float* __restrict__ wi,
                                              float* __restrict__ xsc) {
  int n = blockIdx.x * 256 + threadIdx.x;
  if (n >= NN) return;
  float F0[16], A[16], B[16];
#pragma unroll
  for (int i = 0; i < 16; ++i) { F0[i] = 0.f; A[i] = 0.f; B[i] = 0.f; }
#pragma unroll
  for (int t = 0; t < 8; ++t) {
    const float* xp = x + ((size_t)t * NN + n) * 28;
    const float ct = CTab[t], st = STab[t];
#pragma unroll
    for (int i = 0; i < 16; ++i) {
      float v = xp[i];
      F0[i] += v;
      A[i] = fmaf(v, ct, A[i]);
      B[i] = fmaf(v, -st, B[i]);
    }
  }
  for (int o = 0; o < 16; ++o) {
    float r0 = 0.f, r1 = 0.f, i1 = 0.f;
#pragma unroll
    for (int i = 0; i < 16; ++i) {
      float wr0 = wr[i * 32 + o * 2 + 0];
      float wr1 = wr[i * 32 + o * 2 + 1];
      float wi1 = wi[i * 32 + o * 2 + 1];
      r0 = fmaf(F0[i], wr0, r0);
      r1 += A[i] * wr1 - B[i] * wi1;
      i1 += A[i] * wi1 + B[i] * wr1;
    }
#pragma unroll
    for (int t = 0; t < 8; ++t) {
      float val = 0.125f * (r0 + 2.f * (r1 * CTab[t] - i1 * STab[t]));
      xsc[((size_t)t * NN + n) * 16 + o] = val;
    }
  }
}

__global__ __launch_bounds__(256) void k_cnt(const int* __restrict__ ei,
                                             float* __restrict__ cnt) {
  int e = blockIdx.x * 256 + threadIdx.x;
  if (e >= EE) return;
  atomAdd(cnt + ei[EE + e], 1.f);
}

// ---------------- fused MFMA edge kernel, latency-optimized ----------------
__global__ __launch_bounds__(256, 4) void k_edge3(
    const float* __restrict__ x,     // (T,N,28)
    const int* __restrict__ ei,      // (2,E)
    const float* __restrict__ eag,   // (T,E,48)
    const float* __restrict__ shg,   // (T,E,4)
    const short* __restrict__ W1F,
    const short* __restrict__ W2F,
    const float* __restrict__ b1,
    const float* __restrict__ b2,
    float* __restrict__ seg)         // (T,N,40)
{
  __shared__ float cSs[16][64];   // s_i*sh0*N0F
  __shared__ float rawSs[16][64]; // s_i
  __shared__ float cVDs[4][64];   // vd_i*N0F
  __shared__ float vS0s[12][64];  // v_i[d]*sh0*INV3*N1OF
  __shared__ float sh1fs[3][64];  // sh1[d]*INV3*N1OF
  __shared__ float cCRs[12][64];  // cross(v_i,sh1)[d]*INV6*N1EF
  __shared__ int   dsts[64];
  __shared__ ushort Hs[4][16][64];

  int blk = blockIdx.x;
  int t = blk >> 9;
  int e0 = (blk & 511) * 64;
  int tid = threadIdx.x;

  // ---- distributed staging: wave w = role w, 64 edges each ----
  {
    int e = tid & 63;
    int role = tid >> 6;
    int eg = e0 + e;
    const float* shp = shg + ((size_t)t * EE + eg) * 4;
    float sh0 = shp[0], s1x = shp[1], s1y = shp[2], s1z = shp[3];
    int src = ei[eg];
    const float* xr = x + ((size_t)t * NN + src) * 28;
    const float F1 = INV3 * N1OF;
    if (role == 0) {
      dsts[e] = ei[EE + eg];
      sh1fs[0][e] = s1x * F1; sh1fs[1][e] = s1y * F1; sh1fs[2][e] = s1z * F1;
#pragma unroll
      for (int i = 0; i < 8; ++i) {
        float s = xr[i];
        rawSs[i][e] = s;
        cSs[i][e] = s * sh0 * N0F;
      }
    } else if (role == 1) {
#pragma unroll
      for (int i = 8; i < 16; ++i) {
        float s = xr[i];
        rawSs[i][e] = s;
        cSs[i][e] = s * sh0 * N0F;
      }
    } else {
      int i0 = (role == 2) ? 0 : 2;
#pragma unroll
      for (int ii = 0; ii < 2; ++ii) {
        int i = i0 + ii;
        float vx = xr[16 + 3 * i], vy = xr[17 + 3 * i], vz = xr[18 + 3 * i];
        cVDs[i][e] = (vx * s1x + vy * s1y + vz * s1z) * INV3 * N0F;
        vS0s[3 * i + 0][e] = vx * sh0 * F1;
        vS0s[3 * i + 1][e] = vy * sh0 * F1;
        vS0s[3 * i + 2][e] = vz * sh0 * F1;
        cCRs[3 * i + 0][e] = (vy * s1z - vz * s1y) * INV6 * N1EF;
        cCRs[3 * i + 1][e] = (vz * s1x - vx * s1z) * INV6 * N1EF;
        cCRs[3 * i + 2][e] = (vx * s1y - vy * s1x) * INV6 * N1EF;
      }
    }
  }
  __syncthreads();

  int w = tid >> 6, l = tid & 63;
  int col = l & 15;
  int kq  = (l >> 4) << 2;
  int eb  = w * 16;

  // ---- GEMM1: H = relu(EA @ W1 + b1) ----
  const float* row = eag + ((size_t)t * EE + e0 + eb + col) * 48;
  float4 fa = *(const float4*)(row + kq);
  float4 fb = *(const float4*)(row + 16 + kq);
  float4 fc = *(const float4*)(row + 32 + kq);
  short8 a0, a1;
  a0[0] = f2bfs(fa.x); a0[1] = f2bfs(fa.y); a0[2] = f2bfs(fa.z); a0[3] = f2bfs(fa.w);
  a0[4] = f2bfs(fb.x); a0[5] = f2bfs(fb.y); a0[6] = f2bfs(fb.z); a0[7] = f2bfs(fb.w);
  a1[0] = f2bfs(fc.x); a1[1] = f2bfs(fc.y); a1[2] = f2bfs(fc.z); a1[3] = f2bfs(fc.w);
  a1[4] = 0; a1[5] = 0; a1[6] = 0; a1[7] = 0;

  const short8* w1f = (const short8*)W1F;
  const short8* w2f = (const short8*)W2F;

#pragma unroll
  for (int nt = 0; nt < 3; ++nt) {
    float bias = b1[nt * 16 + col];
    f32x4 c = {bias, bias, bias, bias};
    c = __builtin_amdgcn_mfma_f32_16x16x32_bf16(a0, w1f[(nt * 2 + 0) * 64 + l], c, 0, 0, 0);
    c = __builtin_amdgcn_mfma_f32_16x16x32_bf16(a1, w1f[(nt * 2 + 1) * 64 + l], c, 0, 0, 0);
#pragma unroll
    for (int r = 0; r < 4; ++r) {
      int m = kq + r;
      float hv = fmaxf(c[r], 0.f);
      Hs[w][m][(nt * 16 + col) ^ ((m & 7) << 3)] = (ushort)f2bfs(hv);
    }
  }
#pragma unroll
  for (int r = 0; r < 4; ++r) {
    int m = kq + r;
    Hs[w][m][(48 + col) ^ ((m & 7) << 3)] = 0;
  }

  // ---- read A-fragments of H ----
  int m2 = col, X = (m2 & 7) << 3;
  ushort4 r0 = *(const ushort4*)&Hs[w][m2][(kq +  0) ^ X];
  ushort4 r1 = *(const ushort4*)&Hs[w][m2][(kq + 16) ^ X];
  ushort4 r2 = *(const ushort4*)&Hs[w][m2][(kq + 32) ^ X];
  ushort4 r3 = *(const ushort4*)&Hs[w][m2][(kq + 48) ^ X];
  short8 A20, A21;
  A20[0] = (short)r0.x; A20[1] = (short)r0.y; A20[2] = (short)r0.z; A20[3] = (short)r0.w;
  A20[4] = (short)r1.x; A20[5] = (short)r1.y; A20[6] = (short)r1.z; A20[7] = (short)r1.w;
  A21[0] = (short)r2.x; A21[1] = (short)r2.y; A21[2] = (short)r2.z; A21[3] = (short)r2.w;
  A21[4] = (short)r3.x; A21[5] = (short)r3.y; A21[6] = (short)r3.z; A21[7] = (short)r3.w;

  // ---- GEMM2: flat 26-chunk loop, 4-deep static prefetch pipeline ----
  float acc0[4]  = {0.f, 0.f, 0.f, 0.f};
  float accP2[4] = {0.f, 0.f, 0.f, 0.f};
  float acc1o[3][4] = {{0.f,0.f,0.f,0.f},{0.f,0.f,0.f,0.f},{0.f,0.f,0.f,0.f}};
  float acc1e[3][4] = {{0.f,0.f,0.f,0.f},{0.f,0.f,0.f,0.f},{0.f,0.f,0.f,0.f}};
  int er0 = eb + kq;
  int iloc = col >> 2;
  int o = col & 3;

  short8 pf0[4], pf1[4];
#pragma unroll
  for (int i = 0; i < 4; ++i) {
    pf0[i] = w2f[(2 * i + 0) * 64 + l];
    pf1[i] = w2f[(2 * i + 1) * 64 + l];
  }

#pragma unroll
  for (int ck = 0; ck < 26; ++ck) {
    short8 B0 = pf0[ck & 3], B1 = pf1[ck & 3];
    if (ck + 4 < 26) {
      pf0[ck & 3] = w2f[(2 * (ck + 4) + 0) * 64 + l];
      pf1[ck & 3] = w2f[(2 * (ck + 4) + 1) * 64 + l];
    }
    float bias = b2[ck * 16 + col];
    f32x4 c = {bias, bias, bias, bias};
    c = __builtin_amdgcn_mfma_f32_16x16x32_bf16(A20, B0, c, 0, 0, 0);
    c = __builtin_amdgcn_mfma_f32_16x16x32_bf16(A21, B1, c, 0, 0, 0);

    if (ck < 16) {
      // w00: coeff = s_i*sh0*N0F, i = ck
#pragma unroll
      for (int r = 0; r < 4; ++r)
        acc0[r] = fmaf(cSs[ck][er0 + r], c[r], acc0[r]);
    } else if (ck < 20) {
      // w01: k=256+4i+o, i=(ck-16)*4+iloc
#pragma unroll
      for (int r = 0; r < 4; ++r) {
        float q = rawSs[(ck - 16) * 4 + iloc][er0 + r] * c[r];
        q += __shfl_xor(q, 4);
        q += __shfl_xor(q, 8);
        accP2[r] += q;
      }
    } else if (ck == 20) {
      // w10: coeff v_i[d]*sh0*INV3*N1OF
#pragma unroll
      for (int d = 0; d < 3; ++d)
#pragma unroll
        for (int r = 0; r < 4; ++r) {
          float q = vS0s[iloc * 3 + d][er0 + r] * c[r];
          q += __shfl_xor(q, 4);
          q += __shfl_xor(q, 8);
          acc1o[d][r] += q;
        }
    } else if (ck < 25) {
      // w110: coeff = vd_i*N0F, i = ck-21
#pragma unroll
      for (int r = 0; r < 4; ++r)
        acc0[r] = fmaf(cVDs[ck - 21][er0 + r], c[r], acc0[r]);
    } else {
      // w111: coeff cr_i[d]
#pragma unroll
      for (int d = 0; d < 3; ++d)
#pragma unroll
        for (int r = 0; r < 4; ++r) {
          float q = cCRs[iloc * 3 + d][er0 + r] * c[r];
          q += __shfl_xor(q, 4);
          q += __shfl_xor(q, 8);
          acc1e[d][r] += q;
        }
    }
  }

  // ---- scatter ----
#pragma unroll
  for (int r = 0; r < 4; ++r) {
    int e = er0 + r;
    float* base = seg + ((size_t)t * NN + dsts[e]) * 40;
    atomAdd(base + col, acc0[r]);
  }
  if (col < 4) {
#pragma unroll
    for (int r = 0; r < 4; ++r) {
      int e = er0 + r;
      float* base = seg + ((size_t)t * NN + dsts[e]) * 40;
#pragma unroll
      for (int d = 0; d < 3; ++d) {
        atomAdd(base + 16 + 3 * o + d, fmaf(accP2[r], sh1fs[d][e], acc1o[d][r]));
        atomAdd(base + 28 + 3 * o + d, acc1e[d][r]);
      }
    }
  }
}

// ---------------- stats + normalize ----------------
__global__ __launch_bounds__(256) void k_stats(float* __restrict__ seg,
                                               const float* __restrict__ cnt,
                                               const float* __restrict__ xsc,
                                               float* __restrict__ stats) {
  int b = blockIdx.x;
  int t = b / 40;
  int chunk = b - t * 40;
  int n = chunk * 256 + threadIdx.x;
  float p[5] = {0.f, 0.f, 0.f, 0.f, 0.f};
  float q[5] = {0.f, 0.f, 0.f, 0.f, 0.f};
  if (n < NN) {
    float rc = 1.f / fmaxf(cnt[n], 1.f);
    float* sp = seg + ((size_t)t * NN + n) * 40;
    const float* xp = xsc + ((size_t)t * NN + n) * 16;
#pragma unroll
    for (int c = 0; c < 40; ++c) {
      float y = sp[c] * rc + (c < 16 ? xp[c] : 0.f);
      sp[c] = y;
      p[c % 5] += y;
      q[c % 5] = fmaf(y, y, q[c % 5]);
    }
  }
#pragma unroll
  for (int r = 0; r < 5; ++r) {
#pragma unroll
    for (int m = 32; m >= 1; m >>= 1) {
      p[r] += __shfl_xor(p[r], m);
      q[r] += __shfl_xor(q[r], m);
    }
  }
  __shared__ float ls[4][10];
  int lane = threadIdx.x & 63, wv = threadIdx.x >> 6;
  if (lane == 0) {
#pragma unroll
    for (int r = 0; r < 5; ++r) { ls[wv][r] = p[r]; ls[wv][5 + r] = q[r]; }
  }
  __syncthreads();
  if (threadIdx.x < 10) {
    int tid = threadIdx.x;
    float sum = ls[0][tid] + ls[1][tid] + ls[2][tid] + ls[3][tid];
    int r = tid % 5;
    int j = 8 * r + t;
    atomAdd(stats + (tid >= 5 ? 40 + j : j), sum);
  }
}

__global__ __launch_bounds__(256) void k_norm(const float* __restrict__ seg,
                                              const float* __restrict__ stats,
                                              const float* __restrict__ gam,
                                              const float* __restrict__ bet,
                                              float* __restrict__ out) {
  int idx = blockIdx.x * 256 + threadIdx.x;
  if (idx >= TT * NN * CC) return;
  int c = idx % 40;
  int t = idx / (NN * CC);
  int j = 8 * (c % 5) + t;
  const float inv = 1.f / (8.f * (float)NN);
  float mu = stats[j] * inv;
  float var = stats[40 + j] * inv - mu * mu;
  float y = seg[idx];
  out[idx] = (y - mu) * rsqrtf(var + EPSV) * gam[j] + bet[j];
}

extern "C" void kernel_launch(void* const* d_in, const int* in_sizes, int n_in,
                              void* d_out, int out_size, void* d_ws, size_t ws_size,
                              hipStream_t stream) {
  const float* x   = (const float*)d_in[0];
  const int*   ei  = (const int*)d_in[1];
  const float* ea  = (const float*)d_in[2];
  const float* esh = (const float*)d_in[3];
  const float* W1  = (const float*)d_in[4];
  const float* b1  = (const float*)d_in[5];
  const float* W2  = (const float*)d_in[6];
  const float* b2  = (const float*)d_in[7];
  const float* wr  = (const float*)d_in[8];
  const float* wi  = (const float*)d_in[9];
  const float* gam = (const float*)d_in[10];
  const float* bet = (const float*)d_in[11];
  float* out = (float*)d_out;

  float* ws    = (float*)d_ws;
  float* seg   = ws;                            // T*N*40
  float* cnt   = seg + (size_t)TT * NN * CC;    // 10,000
  float* stats = cnt + NN;                      // 80
  float* xsc   = stats + 80;                    // T*N*16
  short* W1F   = (short*)(xsc + (size_t)TT * NN * 16);
  short* W2F   = W1F + 3 * 2 * 64 * 8;

  hipMemsetAsync(seg, 0, ((size_t)TT * NN * CC + NN + 80) * sizeof(float), stream);

  k_prep<<<(29696 + 255) / 256, 256, 0, stream>>>(W1, W2, W1F, W2F);
  k_spec<<<(NN + 255) / 256, 256, 0, stream>>>(x, wr, wi, xsc);
  k_cnt<<<EE / 256, 256, 0, stream>>>(ei, cnt);
  k_edge3<<<TT * (EE / 64), 256, 0, stream>>>(x, ei, ea, esh, W1F, W2F, b1, b2, seg);
  k_stats<<<8 * 40, 256, 0, stream>>>(seg, cnt, xsc, stats);
  k_norm<<<(TT * NN * CC + 255) / 256, 256, 0, stream>>>(seg, stats, gam, bet, out);
}

// Round 4
// 182.366 us; speedup vs baseline: 1.2455x; 1.2455x over previous
//
#include <hip/hip_runtime.h>
#include <math.h>

#define TT 8
#define NN 10000
#define EE 32768
#define CC 40
#define EPSV 1e-05f

constexpr float INV3 = 0.57735026918962576f;
constexpr float INV6 = 0.40824829046386302f;
constexpr float N0F  = 0.22360679774997896f;
constexpr float N1OF = 0.22360679774997896f;
constexpr float N1EF = 0.5f;

constexpr float CTab[8] = {1.f, 0.70710678118654752f, 0.f, -0.70710678118654752f,
                           -1.f, -0.70710678118654752f, 0.f, 0.70710678118654752f};
constexpr float STab[8] = {0.f, 0.70710678118654752f, 1.f, 0.70710678118654752f,
                           0.f, -0.70710678118654752f, -1.f, -0.70710678118654752f};

typedef __attribute__((ext_vector_type(8))) short short8;
typedef __attribute__((ext_vector_type(4))) float f32x4;

__device__ __forceinline__ void atomAdd(float* p, float v) {
  __hip_atomic_fetch_add(p, v, __ATOMIC_RELAXED, __HIP_MEMORY_SCOPE_AGENT);
}

// fp32 -> bf16 bits (RNE)
__device__ __forceinline__ short f2bfs(float f) {
  unsigned u = __builtin_bit_cast(unsigned, f);
  u = (u + 0x7fffu + ((u >> 16) & 1u)) >> 16;
  return (short)u;
}
__device__ __forceinline__ float bf2f(ushort u) {
  unsigned v = ((unsigned)u) << 16;
  return __builtin_bit_cast(float, v);
}

// ---------------- pack W1 (48x48) and W2 (48x416) into MFMA B-fragment order, bf16 ----
__global__ __launch_bounds__(256) void k_prep(const float* __restrict__ W1,
                                              const float* __restrict__ W2,
                                              short* __restrict__ W1F,
                                              short* __restrict__ W2F) {
  int idx = blockIdx.x * 256 + threadIdx.x;
  const int tot1 = 3 * 2 * 64 * 8;
  const int tot2 = 26 * 2 * 64 * 8;
  if (idx < tot1) {
    int elem = idx & 7, lane = (idx >> 3) & 63, kt = (idx >> 9) & 1, nt = idx >> 10;
    int j = kt * 32 + ((lane >> 4) << 2) + (elem & 3) + ((elem >> 2) << 4);
    int n = nt * 16 + (lane & 15);
    W1F[idx] = (j < 48) ? f2bfs(W1[j * 48 + n]) : (short)0;
  } else if (idx < tot1 + tot2) {
    int id2 = idx - tot1;
    int elem = id2 & 7, lane = (id2 >> 3) & 63, kt = (id2 >> 9) & 1, ck = id2 >> 10;
    int j = kt * 32 + ((lane >> 4) << 2) + (elem & 3) + ((elem >> 2) << 4);
    int n = ck * 16 + (lane & 15);
    W2F[id2] = (j < 48) ? f2bfs(W2[j * 416 + n]) : (short)0;
  }
}

// ---------------- spectral conv ----------------
__global__ __launch_bounds__(256) void k_spec(const float* __restrict__ x,
                                              const float* __restrict__ wr,
                                              const float* __restrict__ wi,
                                              float* __restrict__ xsc) {
  int n = blockIdx.x * 256 + threadIdx.x;
  if (n >= NN) return;
  float F0[16], A[16], B[16];
#pragma unroll
  for (int i = 0; i < 16; ++i) { F0[i] = 0.f; A[i] = 0.f; B[i] = 0.f; }
#pragma unroll
  for (int t = 0; t < 8; ++t) {
    const float* xp = x + ((size_t)t * NN + n) * 28;
    const float ct = CTab[t], st = STab[t];
#pragma unroll
    for (int i = 0; i < 16; ++i) {
      float v = xp[i];
      F0[i] += v;
      A[i] = fmaf(v, ct, A[i]);
      B[i] = fmaf(v, -st, B[i]);
    }
  }
  for (int o = 0; o < 16; ++o) {
    float r0 = 0.f, r1 = 0.f, i1 = 0.f;
#pragma unroll
    for (int i = 0; i < 16; ++i) {
      float wr0 = wr[i * 32 + o * 2 + 0];
      float wr1 = wr[i * 32 + o * 2 + 1];
      float wi1 = wi[i * 32 + o * 2 + 1];
      r0 = fmaf(F0[i], wr0, r0);
      r1 += A[i] * wr1 - B[i] * wi1;
      i1 += A[i] * wi1 + B[i] * wr1;
    }
#pragma unroll
    for (int t = 0; t < 8; ++t) {
      float val = 0.125f * (r0 + 2.f * (r1 * CTab[t] - i1 * STab[t]));
      xsc[((size_t)t * NN + n) * 16 + o] = val;
    }
  }
}

// ---------------- CSR build ----------------
__global__ __launch_bounds__(256) void k_deg(const int* __restrict__ ei,
                                             int* __restrict__ deg) {
  int e = blockIdx.x * 256 + threadIdx.x;
  if (e >= EE) return;
  atomicAdd(&deg[ei[EE + e]], 1);
}

__global__ __launch_bounds__(256) void k_scan(const int* __restrict__ deg,
                                              int* __restrict__ row_start,
                                              int* __restrict__ cursor) {
  __shared__ int sums[256];
  int tid = threadIdx.x;
  const int PER = 40;  // 256*40 >= NN
  int base = tid * PER;
  int s = 0;
  for (int i = 0; i < PER; ++i) {
    int idx = base + i;
    if (idx < NN) s += deg[idx];
  }
  sums[tid] = s;
  __syncthreads();
  for (int off = 1; off < 256; off <<= 1) {
    int add = (tid >= off) ? sums[tid - off] : 0;
    __syncthreads();
    sums[tid] += add;
    __syncthreads();
  }
  int run = sums[tid] - s;  // exclusive prefix
  for (int i = 0; i < PER; ++i) {
    int idx = base + i;
    if (idx < NN) {
      row_start[idx] = run;
      cursor[idx] = run;
      run += deg[idx];
    }
  }
  if (tid == 255) row_start[NN] = run;
}

__global__ __launch_bounds__(256) void k_bucket(const int* __restrict__ ei,
                                                int* __restrict__ cursor,
                                                int* __restrict__ perm) {
  int e = blockIdx.x * 256 + threadIdx.x;
  if (e >= EE) return;
  int d = ei[EE + e];
  int slot = atomicAdd(&cursor[d], 1);
  perm[slot] = e;
}

// ---------------- fused MFMA edge kernel -> dense msg (no atomics) ----------------
__global__ __launch_bounds__(256, 4) void k_edge4(
    const float* __restrict__ x,     // (T,N,28)
    const int* __restrict__ ei,      // (2,E)
    const float* __restrict__ eag,   // (T,E,48)
    const float* __restrict__ shg,   // (T,E,4)
    const short* __restrict__ W1F,
    const short* __restrict__ W2F,
    const float* __restrict__ b1,
    const float* __restrict__ b2,
    ushort* __restrict__ msg)        // (T,E,40) bf16
{
  __shared__ float cSs[16][64];   // s_i*sh0*N0F
  __shared__ float rawSs[16][64]; // s_i
  __shared__ float cVDs[4][64];   // vd_i*N0F
  __shared__ float vS0s[12][64];  // v_i[d]*sh0*INV3*N1OF
  __shared__ float sh1fs[3][64];  // sh1[d]*INV3*N1OF
  __shared__ float cCRs[12][64];  // cross(v_i,sh1)[d]*INV6*N1EF
  __shared__ ushort Hs[4][16][64];

  int blk = blockIdx.x;
  int t = blk >> 9;
  int e0 = (blk & 511) * 64;
  int tid = threadIdx.x;

  // ---- distributed staging ----
  {
    int e = tid & 63;
    int role = tid >> 6;
    int eg = e0 + e;
    const float* shp = shg + ((size_t)t * EE + eg) * 4;
    float sh0 = shp[0], s1x = shp[1], s1y = shp[2], s1z = shp[3];
    int src = ei[eg];
    const float* xr = x + ((size_t)t * NN + src) * 28;
    const float F1 = INV3 * N1OF;
    if (role == 0) {
      sh1fs[0][e] = s1x * F1; sh1fs[1][e] = s1y * F1; sh1fs[2][e] = s1z * F1;
#pragma unroll
      for (int i = 0; i < 8; ++i) {
        float s = xr[i];
        rawSs[i][e] = s;
        cSs[i][e] = s * sh0 * N0F;
      }
    } else if (role == 1) {
#pragma unroll
      for (int i = 8; i < 16; ++i) {
        float s = xr[i];
        rawSs[i][e] = s;
        cSs[i][e] = s * sh0 * N0F;
      }
    } else {
      int i0 = (role == 2) ? 0 : 2;
#pragma unroll
      for (int ii = 0; ii < 2; ++ii) {
        int i = i0 + ii;
        float vx = xr[16 + 3 * i], vy = xr[17 + 3 * i], vz = xr[18 + 3 * i];
        cVDs[i][e] = (vx * s1x + vy * s1y + vz * s1z) * INV3 * N0F;
        vS0s[3 * i + 0][e] = vx * sh0 * F1;
        vS0s[3 * i + 1][e] = vy * sh0 * F1;
        vS0s[3 * i + 2][e] = vz * sh0 * F1;
        cCRs[3 * i + 0][e] = (vy * s1z - vz * s1y) * INV6 * N1EF;
        cCRs[3 * i + 1][e] = (vz * s1x - vx * s1z) * INV6 * N1EF;
        cCRs[3 * i + 2][e] = (vx * s1y - vy * s1x) * INV6 * N1EF;
      }
    }
  }
  __syncthreads();

  int w = tid >> 6, l = tid & 63;
  int col = l & 15;
  int kq  = (l >> 4) << 2;
  int eb  = w * 16;

  // ---- GEMM1: H = relu(EA @ W1 + b1) ----
  const float* row = eag + ((size_t)t * EE + e0 + eb + col) * 48;
  float4 fa = *(const float4*)(row + kq);
  float4 fb = *(const float4*)(row + 16 + kq);
  float4 fc = *(const float4*)(row + 32 + kq);
  short8 a0, a1;
  a0[0] = f2bfs(fa.x); a0[1] = f2bfs(fa.y); a0[2] = f2bfs(fa.z); a0[3] = f2bfs(fa.w);
  a0[4] = f2bfs(fb.x); a0[5] = f2bfs(fb.y); a0[6] = f2bfs(fb.z); a0[7] = f2bfs(fb.w);
  a1[0] = f2bfs(fc.x); a1[1] = f2bfs(fc.y); a1[2] = f2bfs(fc.z); a1[3] = f2bfs(fc.w);
  a1[4] = 0; a1[5] = 0; a1[6] = 0; a1[7] = 0;

  const short8* w1f = (const short8*)W1F;
  const short8* w2f = (const short8*)W2F;

#pragma unroll
  for (int nt = 0; nt < 3; ++nt) {
    float bias = b1[nt * 16 + col];
    f32x4 c = {bias, bias, bias, bias};
    c = __builtin_amdgcn_mfma_f32_16x16x32_bf16(a0, w1f[(nt * 2 + 0) * 64 + l], c, 0, 0, 0);
    c = __builtin_amdgcn_mfma_f32_16x16x32_bf16(a1, w1f[(nt * 2 + 1) * 64 + l], c, 0, 0, 0);
#pragma unroll
    for (int r = 0; r < 4; ++r) {
      int m = kq + r;
      float hv = fmaxf(c[r], 0.f);
      Hs[w][m][(nt * 16 + col) ^ ((m & 7) << 3)] = (ushort)f2bfs(hv);
    }
  }
#pragma unroll
  for (int r = 0; r < 4; ++r) {
    int m = kq + r;
    Hs[w][m][(48 + col) ^ ((m & 7) << 3)] = 0;
  }

  // ---- read A-fragments of H ----
  int m2 = col, X = (m2 & 7) << 3;
  ushort4 r0 = *(const ushort4*)&Hs[w][m2][(kq +  0) ^ X];
  ushort4 r1 = *(const ushort4*)&Hs[w][m2][(kq + 16) ^ X];
  ushort4 r2 = *(const ushort4*)&Hs[w][m2][(kq + 32) ^ X];
  ushort4 r3 = *(const ushort4*)&Hs[w][m2][(kq + 48) ^ X];
  short8 A20, A21;
  A20[0] = (short)r0.x; A20[1] = (short)r0.y; A20[2] = (short)r0.z; A20[3] = (short)r0.w;
  A20[4] = (short)r1.x; A20[5] = (short)r1.y; A20[6] = (short)r1.z; A20[7] = (short)r1.w;
  A21[0] = (short)r2.x; A21[1] = (short)r2.y; A21[2] = (short)r2.z; A21[3] = (short)r2.w;
  A21[4] = (short)r3.x; A21[5] = (short)r3.y; A21[6] = (short)r3.z; A21[7] = (short)r3.w;

  // ---- GEMM2: flat 26-chunk loop, register prefetch ----
  float acc0[4]  = {0.f, 0.f, 0.f, 0.f};
  float accP2[4] = {0.f, 0.f, 0.f, 0.f};
  float acc1o[3][4] = {{0.f,0.f,0.f,0.f},{0.f,0.f,0.f,0.f},{0.f,0.f,0.f,0.f}};
  float acc1e[3][4] = {{0.f,0.f,0.f,0.f},{0.f,0.f,0.f,0.f},{0.f,0.f,0.f,0.f}};
  int er0 = eb + kq;
  int iloc = col >> 2;
  int o = col & 3;

  short8 pf0[4], pf1[4];
#pragma unroll
  for (int i = 0; i < 4; ++i) {
    pf0[i] = w2f[(2 * i + 0) * 64 + l];
    pf1[i] = w2f[(2 * i + 1) * 64 + l];
  }

#pragma unroll
  for (int ck = 0; ck < 26; ++ck) {
    short8 B0 = pf0[ck & 3], B1 = pf1[ck & 3];
    if (ck + 4 < 26) {
      pf0[ck & 3] = w2f[(2 * (ck + 4) + 0) * 64 + l];
      pf1[ck & 3] = w2f[(2 * (ck + 4) + 1) * 64 + l];
    }
    float bias = b2[ck * 16 + col];
    f32x4 c = {bias, bias, bias, bias};
    c = __builtin_amdgcn_mfma_f32_16x16x32_bf16(A20, B0, c, 0, 0, 0);
    c = __builtin_amdgcn_mfma_f32_16x16x32_bf16(A21, B1, c, 0, 0, 0);

    if (ck < 16) {
#pragma unroll
      for (int r = 0; r < 4; ++r)
        acc0[r] = fmaf(cSs[ck][er0 + r], c[r], acc0[r]);
    } else if (ck < 20) {
#pragma unroll
      for (int r = 0; r < 4; ++r) {
        float q = rawSs[(ck - 16) * 4 + iloc][er0 + r] * c[r];
        q += __shfl_xor(q, 4);
        q += __shfl_xor(q, 8);
        accP2[r] += q;
      }
    } else if (ck == 20) {
#pragma unroll
      for (int d = 0; d < 3; ++d)
#pragma unroll
        for (int r = 0; r < 4; ++r) {
          float q = vS0s[iloc * 3 + d][er0 + r] * c[r];
          q += __shfl_xor(q, 4);
          q += __shfl_xor(q, 8);
          acc1o[d][r] += q;
        }
    } else if (ck < 25) {
#pragma unroll
      for (int r = 0; r < 4; ++r)
        acc0[r] = fmaf(cVDs[ck - 21][er0 + r], c[r], acc0[r]);
    } else {
#pragma unroll
      for (int d = 0; d < 3; ++d)
#pragma unroll
        for (int r = 0; r < 4; ++r) {
          float q = cCRs[iloc * 3 + d][er0 + r] * c[r];
          q += __shfl_xor(q, 4);
          q += __shfl_xor(q, 8);
          acc1e[d][r] += q;
        }
    }
  }

  // ---- dense stores (no atomics) ----
#pragma unroll
  for (int r = 0; r < 4; ++r) {
    size_t eg = (size_t)t * EE + e0 + er0 + r;
    msg[eg * 40 + col] = (ushort)f2bfs(acc0[r]);
  }
  if (col < 4) {
#pragma unroll
    for (int r = 0; r < 4; ++r) {
      int e = er0 + r;
      size_t eg = (size_t)t * EE + e0 + e;
      ushort* mrow = msg + eg * 40;
#pragma unroll
      for (int d = 0; d < 3; ++d) {
        mrow[16 + 3 * o + d] = (ushort)f2bfs(fmaf(accP2[r], sh1fs[d][e], acc1o[d][r]));
        mrow[28 + 3 * o + d] = (ushort)f2bfs(acc1e[d][r]);
      }
    }
  }
}

// ---------------- gather: per (t,node,col) sum incident msgs, mean, +xsc ----------------
__global__ __launch_bounds__(320) void k_gather(const ushort* __restrict__ msg,
                                                const int* __restrict__ row_start,
                                                const int* __restrict__ perm,
                                                const float* __restrict__ xsc,
                                                float* __restrict__ out) {
  int tid = threadIdx.x;
  int blk = blockIdx.x;          // t*1250 + nb
  int t = blk / 1250;
  int nb = blk - t * 1250;
  int nloc = tid / 40, c = tid - nloc * 40;
  int n = nb * 8 + nloc;
  int a = row_start[n], b = row_start[n + 1];
  float acc = 0.f;
  for (int j = a; j < b; ++j) {
    int e = perm[j];
    acc += bf2f(msg[((size_t)t * EE + e) * 40 + c]);
  }
  float rc = 1.f / fmaxf((float)(b - a), 1.f);
  float y = acc * rc + (c < 16 ? xsc[((size_t)t * NN + n) * 16 + c] : 0.f);
  out[((size_t)t * NN + n) * 40 + c] = y;
}

// ---------------- BN stats ----------------
__global__ __launch_bounds__(256) void k_stats(const float* __restrict__ out,
                                               float* __restrict__ stats) {
  int b = blockIdx.x;
  int t = b / 40;
  int chunk = b - t * 40;
  int n = chunk * 256 + threadIdx.x;
  float p[5] = {0.f, 0.f, 0.f, 0.f, 0.f};
  float q[5] = {0.f, 0.f, 0.f, 0.f, 0.f};
  if (n < NN) {
    const float* sp = out + ((size_t)t * NN + n) * 40;
#pragma unroll
    for (int c = 0; c < 40; ++c) {
      float y = sp[c];
      p[c % 5] += y;
      q[c % 5] = fmaf(y, y, q[c % 5]);
    }
  }
#pragma unroll
  for (int r = 0; r < 5; ++r) {
#pragma unroll
    for (int m = 32; m >= 1; m >>= 1) {
      p[r] += __shfl_xor(p[r], m);
      q[r] += __shfl_xor(q[r], m);
    }
  }
  __shared__ float ls[4][10];
  int lane = threadIdx.x & 63, wv = threadIdx.x >> 6;
  if (lane == 0) {
#pragma unroll
    for (int r = 0; r < 5; ++r) { ls[wv][r] = p[r]; ls[wv][5 + r] = q[r]; }
  }
  __syncthreads();
  if (threadIdx.x < 10) {
    int tid = threadIdx.x;
    float sum = ls[0][tid] + ls[1][tid] + ls[2][tid] + ls[3][tid];
    int r = tid % 5;
    int j = 8 * r + t;
    atomAdd(stats + (tid >= 5 ? 40 + j : j), sum);
  }
}

// ---------------- normalize (in place on out) ----------------
__global__ __launch_bounds__(256) void k_norm(const float* __restrict__ stats,
                                              const float* __restrict__ gam,
                                              const float* __restrict__ bet,
                                              float* __restrict__ out) {
  int idx = blockIdx.x * 256 + threadIdx.x;
  if (idx >= TT * NN * CC) return;
  int c = idx % 40;
  int t = idx / (NN * CC);
  int j = 8 * (c % 5) + t;
  const float inv = 1.f / (8.f * (float)NN);
  float mu = stats[j] * inv;
  float var = stats[40 + j] * inv - mu * mu;
  float y = out[idx];
  out[idx] = (y - mu) * rsqrtf(var + EPSV) * gam[j] + bet[j];
}

extern "C" void kernel_launch(void* const* d_in, const int* in_sizes, int n_in,
                              void* d_out, int out_size, void* d_ws, size_t ws_size,
                              hipStream_t stream) {
  const float* x   = (const float*)d_in[0];
  const int*   ei  = (const int*)d_in[1];
  const float* ea  = (const float*)d_in[2];
  const float* esh = (const float*)d_in[3];
  const float* W1  = (const float*)d_in[4];
  const float* b1  = (const float*)d_in[5];
  const float* W2  = (const float*)d_in[6];
  const float* b2  = (const float*)d_in[7];
  const float* wr  = (const float*)d_in[8];
  const float* wi  = (const float*)d_in[9];
  const float* gam = (const float*)d_in[10];
  const float* bet = (const float*)d_in[11];
  float* out = (float*)d_out;

  float*  xsc       = (float*)d_ws;                       // 1,280,000 f
  ushort* W1F       = (ushort*)(xsc + 1280000);           // 3,072
  ushort* W2F       = W1F + 3072;                         // 26,624
  ushort* msg       = W2F + 26624;                        // 10,485,760
  float*  stats     = (float*)(msg + (size_t)10485760);   // 80
  int*    deg       = (int*)(stats + 80);                 // 10,000
  int*    cursor    = deg + 10000;                        // 10,000
  int*    row_start = cursor + 10000;                     // 10,001
  int*    perm      = row_start + 10001;                  // 32,768

  // zero stats + deg + cursor (contiguous)
  hipMemsetAsync(stats, 0, (80 + 10000 + 10000) * sizeof(int), stream);

  k_prep<<<(29696 + 255) / 256, 256, 0, stream>>>(W1, W2, (short*)W1F, (short*)W2F);
  k_spec<<<(NN + 255) / 256, 256, 0, stream>>>(x, wr, wi, xsc);
  k_deg<<<EE / 256, 256, 0, stream>>>(ei, deg);
  k_scan<<<1, 256, 0, stream>>>(deg, row_start, cursor);
  k_bucket<<<EE / 256, 256, 0, stream>>>(ei, cursor, perm);
  k_edge4<<<TT * (EE / 64), 256, 0, stream>>>(x, ei, ea, esh, (short*)W1F, (short*)W2F,
                                              b1, b2, msg);
  k_gather<<<TT * 1250, 320, 0, stream>>>(msg, row_start, perm, xsc, out);
  k_stats<<<8 * 40, 256, 0, stream>>>(out, stats);
  k_norm<<<(TT * NN * CC + 255) / 256, 256, 0, stream>>>(stats, gam, bet, out);
}

// Round 6
// 150.106 us; speedup vs baseline: 1.5132x; 1.2149x over previous
//
#include <hip/hip_runtime.h>
#include <math.h>

#define TT 8
#define NN 10000
#define EE 32768
#define CC 40
#define EPSV 1e-05f

constexpr float INV3 = 0.57735026918962576f;
constexpr float INV6 = 0.40824829046386302f;
constexpr float N0F  = 0.22360679774997896f;
constexpr float N1OF = 0.22360679774997896f;
constexpr float N1EF = 0.5f;

constexpr float CTab[8] = {1.f, 0.70710678118654752f, 0.f, -0.70710678118654752f,
                           -1.f, -0.70710678118654752f, 0.f, 0.70710678118654752f};
constexpr float STab[8] = {0.f, 0.70710678118654752f, 1.f, 0.70710678118654752f,
                           0.f, -0.70710678118654752f, -1.f, -0.70710678118654752f};

typedef __attribute__((ext_vector_type(8))) short short8;
typedef __attribute__((ext_vector_type(4))) float f32x4;

__device__ __forceinline__ void atomAdd(float* p, float v) {
  __hip_atomic_fetch_add(p, v, __ATOMIC_RELAXED, __HIP_MEMORY_SCOPE_AGENT);
}

__device__ __forceinline__ short f2bfs(float f) {
  unsigned u = __builtin_bit_cast(unsigned, f);
  u = (u + 0x7fffu + ((u >> 16) & 1u)) >> 16;
  return (short)u;
}
__device__ __forceinline__ float bf2f(ushort u) {
  unsigned v = ((unsigned)u) << 16;
  return __builtin_bit_cast(float, v);
}

// ---------------- pack W1 (48x48) and W2 (48x416) into MFMA B-fragment order, bf16 ----
__global__ __launch_bounds__(256) void k_prep(const float* __restrict__ W1,
                                              const float* __restrict__ W2,
                                              short* __restrict__ W1F,
                                              short* __restrict__ W2F) {
  int idx = blockIdx.x * 256 + threadIdx.x;
  const int tot1 = 3 * 2 * 64 * 8;
  const int tot2 = 26 * 2 * 64 * 8;
  if (idx < tot1) {
    int elem = idx & 7, lane = (idx >> 3) & 63, kt = (idx >> 9) & 1, nt = idx >> 10;
    int j = kt * 32 + ((lane >> 4) << 2) + (elem & 3) + ((elem >> 2) << 4);
    int n = nt * 16 + (lane & 15);
    W1F[idx] = (j < 48) ? f2bfs(W1[j * 48 + n]) : (short)0;
  } else if (idx < tot1 + tot2) {
    int id2 = idx - tot1;
    int elem = id2 & 7, lane = (id2 >> 3) & 63, kt = (id2 >> 9) & 1, ck = id2 >> 10;
    int j = kt * 32 + ((lane >> 4) << 2) + (elem & 3) + ((elem >> 2) << 4);
    int n = ck * 16 + (lane & 15);
    W2F[id2] = (j < 48) ? f2bfs(W2[j * 416 + n]) : (short)0;
  }
}

// ---------------- spectral conv, 4 threads per node (thread = (n, o-quad)) ----------------
__global__ __launch_bounds__(256) void k_spec(const float* __restrict__ x,
                                              const float* __restrict__ wr,
                                              const float* __restrict__ wi,
                                              float* __restrict__ xsc) {
  int gid = blockIdx.x * 256 + threadIdx.x;
  int n = gid >> 2, og = gid & 3;
  if (n >= NN) return;
  float F0[16], A[16], B[16];
#pragma unroll
  for (int i = 0; i < 16; ++i) { F0[i] = 0.f; A[i] = 0.f; B[i] = 0.f; }
#pragma unroll
  for (int t = 0; t < 8; ++t) {
    const float* xp = x + ((size_t)t * NN + n) * 28;
    const float ct = CTab[t], st = STab[t];
#pragma unroll
    for (int i = 0; i < 16; ++i) {
      float v = xp[i];
      F0[i] += v;
      A[i] = fmaf(v, ct, A[i]);
      B[i] = fmaf(v, -st, B[i]);
    }
  }
#pragma unroll
  for (int oo = 0; oo < 4; ++oo) {
    int o = og * 4 + oo;
    float r0 = 0.f, r1 = 0.f, i1 = 0.f;
#pragma unroll
    for (int i = 0; i < 16; ++i) {
      float wr0 = wr[i * 32 + o * 2 + 0];
      float wr1 = wr[i * 32 + o * 2 + 1];
      float wi1 = wi[i * 32 + o * 2 + 1];
      r0 = fmaf(F0[i], wr0, r0);
      r1 += A[i] * wr1 - B[i] * wi1;
      i1 += A[i] * wi1 + B[i] * wr1;
    }
#pragma unroll
    for (int t = 0; t < 8; ++t) {
      float val = 0.125f * (r0 + 2.f * (r1 * CTab[t] - i1 * STab[t]));
      xsc[((size_t)t * NN + n) * 16 + o] = val;
    }
  }
}

// ---------------- CSR build ----------------
__global__ __launch_bounds__(256) void k_deg(const int* __restrict__ ei,
                                             int* __restrict__ deg) {
  int e = blockIdx.x * 256 + threadIdx.x;
  if (e >= EE) return;
  atomicAdd(&deg[ei[EE + e]], 1);
}

__global__ __launch_bounds__(1024) void k_scan(const int* __restrict__ deg,
                                               int* __restrict__ row_start,
                                               int* __restrict__ cursor) {
  __shared__ int sums[1024];
  int tid = threadIdx.x;
  const int PER = 10;  // 1024*10 >= NN
  int base = tid * PER;
  int s = 0;
#pragma unroll
  for (int i = 0; i < PER; ++i) {
    int idx = base + i;
    if (idx < NN) s += deg[idx];
  }
  sums[tid] = s;
  __syncthreads();
  for (int off = 1; off < 1024; off <<= 1) {
    int add = (tid >= off) ? sums[tid - off] : 0;
    __syncthreads();
    sums[tid] += add;
    __syncthreads();
  }
  int run = sums[tid] - s;  // exclusive prefix
#pragma unroll
  for (int i = 0; i < PER; ++i) {
    int idx = base + i;
    if (idx < NN) {
      row_start[idx] = run;
      cursor[idx] = run;
      run += deg[idx];
    }
  }
  if (tid == 1023) row_start[NN] = run;
}

__global__ __launch_bounds__(256) void k_bucket(const int* __restrict__ ei,
                                                int* __restrict__ cursor,
                                                int* __restrict__ perm) {
  int e = blockIdx.x * 256 + threadIdx.x;
  if (e >= EE) return;
  int d = ei[EE + e];
  int slot = atomicAdd(&cursor[d], 1);
  perm[slot] = e;
}

// ---------------- fused MFMA edge kernel -> dense msg (no atomics) [round-4 verbatim] ----
__global__ __launch_bounds__(256, 4) void k_edge4(
    const float* __restrict__ x,     // (T,N,28)
    const int* __restrict__ ei,      // (2,E)
    const float* __restrict__ eag,   // (T,E,48)
    const float* __restrict__ shg,   // (T,E,4)
    const short* __restrict__ W1F,
    const short* __restrict__ W2F,
    const float* __restrict__ b1,
    const float* __restrict__ b2,
    ushort* __restrict__ msg)        // (T,E,40) bf16
{
  __shared__ float cSs[16][64];   // s_i*sh0*N0F
  __shared__ float rawSs[16][64]; // s_i
  __shared__ float cVDs[4][64];   // vd_i*N0F
  __shared__ float vS0s[12][64];  // v_i[d]*sh0*INV3*N1OF
  __shared__ float sh1fs[3][64];  // sh1[d]*INV3*N1OF
  __shared__ float cCRs[12][64];  // cross(v_i,sh1)[d]*INV6*N1EF
  __shared__ ushort Hs[4][16][64];

  int blk = blockIdx.x;
  int t = blk >> 9;
  int e0 = (blk & 511) * 64;
  int tid = threadIdx.x;

  // ---- distributed staging ----
  {
    int e = tid & 63;
    int role = tid >> 6;
    int eg = e0 + e;
    const float* shp = shg + ((size_t)t * EE + eg) * 4;
    float sh0 = shp[0], s1x = shp[1], s1y = shp[2], s1z = shp[3];
    int src = ei[eg];
    const float* xr = x + ((size_t)t * NN + src) * 28;
    const float F1 = INV3 * N1OF;
    if (role == 0) {
      sh1fs[0][e] = s1x * F1; sh1fs[1][e] = s1y * F1; sh1fs[2][e] = s1z * F1;
#pragma unroll
      for (int i = 0; i < 8; ++i) {
        float s = xr[i];
        rawSs[i][e] = s;
        cSs[i][e] = s * sh0 * N0F;
      }
    } else if (role == 1) {
#pragma unroll
      for (int i = 8; i < 16; ++i) {
        float s = xr[i];
        rawSs[i][e] = s;
        cSs[i][e] = s * sh0 * N0F;
      }
    } else {
      int i0 = (role == 2) ? 0 : 2;
#pragma unroll
      for (int ii = 0; ii < 2; ++ii) {
        int i = i0 + ii;
        float vx = xr[16 + 3 * i], vy = xr[17 + 3 * i], vz = xr[18 + 3 * i];
        cVDs[i][e] = (vx * s1x + vy * s1y + vz * s1z) * INV3 * N0F;
        vS0s[3 * i + 0][e] = vx * sh0 * F1;
        vS0s[3 * i + 1][e] = vy * sh0 * F1;
        vS0s[3 * i + 2][e] = vz * sh0 * F1;
        cCRs[3 * i + 0][e] = (vy * s1z - vz * s1y) * INV6 * N1EF;
        cCRs[3 * i + 1][e] = (vz * s1x - vx * s1z) * INV6 * N1EF;
        cCRs[3 * i + 2][e] = (vx * s1y - vy * s1x) * INV6 * N1EF;
      }
    }
  }
  __syncthreads();

  int w = tid >> 6, l = tid & 63;
  int col = l & 15;
  int kq  = (l >> 4) << 2;
  int eb  = w * 16;

  // ---- GEMM1: H = relu(EA @ W1 + b1) ----
  const float* row = eag + ((size_t)t * EE + e0 + eb + col) * 48;
  float4 fa = *(const float4*)(row + kq);
  float4 fb = *(const float4*)(row + 16 + kq);
  float4 fc = *(const float4*)(row + 32 + kq);
  short8 a0, a1;
  a0[0] = f2bfs(fa.x); a0[1] = f2bfs(fa.y); a0[2] = f2bfs(fa.z); a0[3] = f2bfs(fa.w);
  a0[4] = f2bfs(fb.x); a0[5] = f2bfs(fb.y); a0[6] = f2bfs(fb.z); a0[7] = f2bfs(fb.w);
  a1[0] = f2bfs(fc.x); a1[1] = f2bfs(fc.y); a1[2] = f2bfs(fc.z); a1[3] = f2bfs(fc.w);
  a1[4] = 0; a1[5] = 0; a1[6] = 0; a1[7] = 0;

  const short8* w1f = (const short8*)W1F;
  const short8* w2f = (const short8*)W2F;

#pragma unroll
  for (int nt = 0; nt < 3; ++nt) {
    float bias = b1[nt * 16 + col];
    f32x4 c = {bias, bias, bias, bias};
    c = __builtin_amdgcn_mfma_f32_16x16x32_bf16(a0, w1f[(nt * 2 + 0) * 64 + l], c, 0, 0, 0);
    c = __builtin_amdgcn_mfma_f32_16x16x32_bf16(a1, w1f[(nt * 2 + 1) * 64 + l], c, 0, 0, 0);
#pragma unroll
    for (int r = 0; r < 4; ++r) {
      int m = kq + r;
      float hv = fmaxf(c[r], 0.f);
      Hs[w][m][(nt * 16 + col) ^ ((m & 7) << 3)] = (ushort)f2bfs(hv);
    }
  }
#pragma unroll
  for (int r = 0; r < 4; ++r) {
    int m = kq + r;
    Hs[w][m][(48 + col) ^ ((m & 7) << 3)] = 0;
  }

  // ---- read A-fragments of H ----
  int m2 = col, X = (m2 & 7) << 3;
  ushort4 r0 = *(const ushort4*)&Hs[w][m2][(kq +  0) ^ X];
  ushort4 r1 = *(const ushort4*)&Hs[w][m2][(kq + 16) ^ X];
  ushort4 r2 = *(const ushort4*)&Hs[w][m2][(kq + 32) ^ X];
  ushort4 r3 = *(const ushort4*)&Hs[w][m2][(kq + 48) ^ X];
  short8 A20, A21;
  A20[0] = (short)r0.x; A20[1] = (short)r0.y; A20[2] = (short)r0.z; A20[3] = (short)r0.w;
  A20[4] = (short)r1.x; A20[5] = (short)r1.y; A20[6] = (short)r1.z; A20[7] = (short)r1.w;
  A21[0] = (short)r2.x; A21[1] = (short)r2.y; A21[2] = (short)r2.z; A21[3] = (short)r2.w;
  A21[4] = (short)r3.x; A21[5] = (short)r3.y; A21[6] = (short)r3.z; A21[7] = (short)r3.w;

  // ---- GEMM2: flat 26-chunk loop, register prefetch, in-loop reduces ----
  float acc0[4]  = {0.f, 0.f, 0.f, 0.f};
  float accP2[4] = {0.f, 0.f, 0.f, 0.f};
  float acc1o[3][4] = {{0.f,0.f,0.f,0.f},{0.f,0.f,0.f,0.f},{0.f,0.f,0.f,0.f}};
  float acc1e[3][4] = {{0.f,0.f,0.f,0.f},{0.f,0.f,0.f,0.f},{0.f,0.f,0.f,0.f}};
  int er0 = eb + kq;
  int iloc = col >> 2;
  int o = col & 3;

  short8 pf0[4], pf1[4];
#pragma unroll
  for (int i = 0; i < 4; ++i) {
    pf0[i] = w2f[(2 * i + 0) * 64 + l];
    pf1[i] = w2f[(2 * i + 1) * 64 + l];
  }

#pragma unroll
  for (int ck = 0; ck < 26; ++ck) {
    short8 B0 = pf0[ck & 3], B1 = pf1[ck & 3];
    if (ck + 4 < 26) {
      pf0[ck & 3] = w2f[(2 * (ck + 4) + 0) * 64 + l];
      pf1[ck & 3] = w2f[(2 * (ck + 4) + 1) * 64 + l];
    }
    float bias = b2[ck * 16 + col];
    f32x4 c = {bias, bias, bias, bias};
    c = __builtin_amdgcn_mfma_f32_16x16x32_bf16(A20, B0, c, 0, 0, 0);
    c = __builtin_amdgcn_mfma_f32_16x16x32_bf16(A21, B1, c, 0, 0, 0);

    if (ck < 16) {
#pragma unroll
      for (int r = 0; r < 4; ++r)
        acc0[r] = fmaf(cSs[ck][er0 + r], c[r], acc0[r]);
    } else if (ck < 20) {
#pragma unroll
      for (int r = 0; r < 4; ++r) {
        float q = rawSs[(ck - 16) * 4 + iloc][er0 + r] * c[r];
        q += __shfl_xor(q, 4);
        q += __shfl_xor(q, 8);
        accP2[r] += q;
      }
    } else if (ck == 20) {
#pragma unroll
      for (int d = 0; d < 3; ++d)
#pragma unroll
        for (int r = 0; r < 4; ++r) {
          float q = vS0s[iloc * 3 + d][er0 + r] * c[r];
          q += __shfl_xor(q, 4);
          q += __shfl_xor(q, 8);
          acc1o[d][r] += q;
        }
    } else if (ck < 25) {
#pragma unroll
      for (int r = 0; r < 4; ++r)
        acc0[r] = fmaf(cVDs[ck - 21][er0 + r], c[r], acc0[r]);
    } else {
#pragma unroll
      for (int d = 0; d < 3; ++d)
#pragma unroll
        for (int r = 0; r < 4; ++r) {
          float q = cCRs[iloc * 3 + d][er0 + r] * c[r];
          q += __shfl_xor(q, 4);
          q += __shfl_xor(q, 8);
          acc1e[d][r] += q;
        }
    }
  }

  // ---- dense stores (no atomics) ----
#pragma unroll
  for (int r = 0; r < 4; ++r) {
    size_t eg = (size_t)t * EE + e0 + er0 + r;
    msg[eg * 40 + col] = (ushort)f2bfs(acc0[r]);
  }
  if (col < 4) {
#pragma unroll
    for (int r = 0; r < 4; ++r) {
      int e = er0 + r;
      size_t eg = (size_t)t * EE + e0 + e;
      ushort* mrow = msg + eg * 40;
#pragma unroll
      for (int d = 0; d < 3; ++d) {
        mrow[16 + 3 * o + d] = (ushort)f2bfs(fmaf(accP2[r], sh1fs[d][e], acc1o[d][r]));
        mrow[28 + 3 * o + d] = (ushort)f2bfs(acc1e[d][r]);
      }
    }
  }
}

// ---------------- gather: per (t,node,col) sum incident msgs, mean, +xsc ----------------
__global__ __launch_bounds__(320) void k_gather(const ushort* __restrict__ msg,
                                                const int* __restrict__ row_start,
                                                const int* __restrict__ perm,
                                                const float* __restrict__ xsc,
                                                float* __restrict__ out) {
  int tid = threadIdx.x;
  int blk = blockIdx.x;          // t*1250 + nb
  int t = blk / 1250;
  int nb = blk - t * 1250;
  int nloc = tid / 40, c = tid - nloc * 40;
  int n = nb * 8 + nloc;
  int a = row_start[n], b = row_start[n + 1];
  float acc = 0.f;
  for (int j = a; j < b; ++j) {
    int e = perm[j];
    acc += bf2f(msg[((size_t)t * EE + e) * 40 + c]);
  }
  float rc = 1.f / fmaxf((float)(b - a), 1.f);
  float y = acc * rc + (c < 16 ? xsc[((size_t)t * NN + n) * 16 + c] : 0.f);
  out[((size_t)t * NN + n) * 40 + c] = y;
}

// ---------------- BN stats ----------------
__global__ __launch_bounds__(256) void k_stats(const float* __restrict__ out,
                                               float* __restrict__ stats) {
  int b = blockIdx.x;
  int t = b / 40;
  int chunk = b - t * 40;
  int n = chunk * 256 + threadIdx.x;
  float p[5] = {0.f, 0.f, 0.f, 0.f, 0.f};
  float q[5] = {0.f, 0.f, 0.f, 0.f, 0.f};
  if (n < NN) {
    const float* sp = out + ((size_t)t * NN + n) * 40;
#pragma unroll
    for (int c = 0; c < 40; ++c) {
      float y = sp[c];
      p[c % 5] += y;
      q[c % 5] = fmaf(y, y, q[c % 5]);
    }
  }
#pragma unroll
  for (int r = 0; r < 5; ++r) {
#pragma unroll
    for (int m = 32; m >= 1; m >>= 1) {
      p[r] += __shfl_xor(p[r], m);
      q[r] += __shfl_xor(q[r], m);
    }
  }
  __shared__ float ls[4][10];
  int lane = threadIdx.x & 63, wv = threadIdx.x >> 6;
  if (lane == 0) {
#pragma unroll
    for (int r = 0; r < 5; ++r) { ls[wv][r] = p[r]; ls[wv][5 + r] = q[r]; }
  }
  __syncthreads();
  if (threadIdx.x < 10) {
    int tid = threadIdx.x;
    float sum = ls[0][tid] + ls[1][tid] + ls[2][tid] + ls[3][tid];
    int r = tid % 5;
    int j = 8 * r + t;
    atomAdd(stats + (tid >= 5 ? 40 + j : j), sum);
  }
}

// ---------------- normalize (float4, in place) ----------------
__global__ __launch_bounds__(256) void k_norm(const float* __restrict__ stats,
                                              const float* __restrict__ gam,
                                              const float* __restrict__ bet,
                                              float* __restrict__ out) {
  int idx4 = blockIdx.x * 256 + threadIdx.x;
  if (idx4 >= TT * NN * 10) return;
  int t = idx4 / (NN * 10);
  int rem = idx4 - t * NN * 10;
  int c0 = (rem % 10) * 4;
  const float inv = 1.f / (8.f * (float)NN);
  float4* op = (float4*)out;
  float4 y = op[idx4];
  float vals[4] = {y.x, y.y, y.z, y.w};
#pragma unroll
  for (int k = 0; k < 4; ++k) {
    int c = c0 + k;
    int j = 8 * (c % 5) + t;
    float mu = stats[j] * inv;
    float var = stats[40 + j] * inv - mu * mu;
    vals[k] = (vals[k] - mu) * rsqrtf(var + EPSV) * gam[j] + bet[j];
  }
  y.x = vals[0]; y.y = vals[1]; y.z = vals[2]; y.w = vals[3];
  op[idx4] = y;
}

extern "C" void kernel_launch(void* const* d_in, const int* in_sizes, int n_in,
                              void* d_out, int out_size, void* d_ws, size_t ws_size,
                              hipStream_t stream) {
  const float* x   = (const float*)d_in[0];
  const int*   ei  = (const int*)d_in[1];
  const float* ea  = (const float*)d_in[2];
  const float* esh = (const float*)d_in[3];
  const float* W1  = (const float*)d_in[4];
  const float* b1  = (const float*)d_in[5];
  const float* W2  = (const float*)d_in[6];
  const float* b2  = (const float*)d_in[7];
  const float* wr  = (const float*)d_in[8];
  const float* wi  = (const float*)d_in[9];
  const float* gam = (const float*)d_in[10];
  const float* bet = (const float*)d_in[11];
  float* out = (float*)d_out;

  float*  xsc       = (float*)d_ws;                       // 1,280,000 f
  ushort* W1F       = (ushort*)(xsc + 1280000);           // 3,072
  ushort* W2F       = W1F + 3072;                         // 26,624
  ushort* msg       = W2F + 26624;                        // 10,485,760
  float*  stats     = (float*)(msg + (size_t)10485760);   // 80
  int*    deg       = (int*)(stats + 80);                 // 10,000
  int*    cursor    = deg + 10000;                        // 10,000
  int*    row_start = cursor + 10000;                     // 10,001
  int*    perm      = row_start + 10001;                  // 32,768

  // zero stats + deg + cursor (contiguous)
  hipMemsetAsync(stats, 0, (80 + 10000 + 10000) * sizeof(int), stream);

  k_prep<<<(29696 + 255) / 256, 256, 0, stream>>>(W1, W2, (short*)W1F, (short*)W2F);
  k_spec<<<(4 * NN + 255) / 256, 256, 0, stream>>>(x, wr, wi, xsc);
  k_deg<<<EE / 256, 256, 0, stream>>>(ei, deg);
  k_scan<<<1, 1024, 0, stream>>>(deg, row_start, cursor);
  k_bucket<<<EE / 256, 256, 0, stream>>>(ei, cursor, perm);
  k_edge4<<<TT * (EE / 64), 256, 0, stream>>>(x, ei, ea, esh, (short*)W1F, (short*)W2F,
                                              b1, b2, msg);
  k_gather<<<TT * 1250, 320, 0, stream>>>(msg, row_start, perm, xsc, out);
  k_stats<<<8 * 40, 256, 0, stream>>>(out, stats);
  k_norm<<<(TT * NN * 10 + 255) / 256, 256, 0, stream>>>(stats, gam, bet, out);
}